// Round 3
// baseline (233.441 us; speedup 1.0000x reference)
//
#include <hip/hip_runtime.h>

// LIF spike scan: x[N, T=32] fp32, scan over contiguous T axis.
//   u = 0.25*u*(1-o_prev) + x_t ;  o = (u > 0.5) ? 1 : 0
// 0.25*u exact (pow2), (1-o) in {0,1} exact -> bit-exact vs numpy fp32 ref.
//
// R5 = R4 with the nontemporal-store type fixed (native ext_vector_type(4)
// float instead of HIP's float4 class, which __builtin_nontemporal_store
// rejects). Design rationale unchanged:
//  - Persistent waves: 512 blocks x 8 tiles each; per-wave 2x8KB LDS dbuf.
//  - Counted s_waitcnt vmcnt(16) (never 0 mid-loop): next tile's 8
//    global_load_lds stay in flight across current tile's scan+store.
//  - Nontemporal output stores: FETCH_SIZE showed the output write-allocating
//    in L3 and evicting half the input; output is never re-read.
//  - Swizzle: linear LDS dest (global_load_lds requirement), pre-swizzled
//    global source, same involution on LDS reads.

constexpr int T = 32;
constexpr float TAU = 0.25f;
constexpr float VTH = 0.5f;
constexpr int QPR = T / 4;                 // 8 float4 per neuron row
constexpr int WAVE_F4 = 64 * QPR;          // 512 float4 per wave-tile (8 KB)
constexpr int BLOCK = 256;
constexpr int WAVES = BLOCK / 64;          // 4 waves/block
constexpr int TILE_F4 = WAVES * WAVE_F4;   // 2048 float4 per block-tile
constexpr int TPB = 8;                     // tiles per block (pipeline depth)

typedef float f32x4 __attribute__((ext_vector_type(4)));  // native vec4

__device__ __forceinline__ int swz(int s) { return s ^ ((s >> 3) & 7); }

__global__ __launch_bounds__(BLOCK) void LIFSpike_kernel(
    const float* __restrict__ x, float* __restrict__ out) {
    __shared__ f32x4 buf[WAVES][2][WAVE_F4];  // 64 KB: per-wave 2x8KB dbuf

    const int t = threadIdx.x;
    const int lane = t & 63;
    const int wid = t >> 6;

    const f32x4* __restrict__ xp = reinterpret_cast<const f32x4*>(x);
    f32x4* __restrict__ op = reinterpret_cast<f32x4*>(out);

    const size_t block_base = (size_t)blockIdx.x * TPB * TILE_F4;  // f4 units

    // Issue 8 async 1KB loads for tile j into ping-pong half pb.
    auto issue_loads = [&](int j, int pb) {
        const size_t tb = block_base + (size_t)j * TILE_F4 + wid * WAVE_F4;
#pragma unroll
        for (int k = 0; k < QPR; ++k) {
            const int p = k * 64;            // wave-uniform LDS f4 base
            const int src = swz(p + lane);   // pre-swizzled global source
            __builtin_amdgcn_global_load_lds(
                (const __attribute__((address_space(1))) void*)(xp + tb + src),
                (__attribute__((address_space(3))) void*)(&buf[wid][pb][p]),
                16, 0, 0);
        }
    };

    issue_loads(0, 0);  // prologue

#pragma unroll
    for (int j = 0; j < TPB; ++j) {
        const int pb = j & 1;
        if (j + 1 < TPB) issue_loads(j + 1, pb ^ 1);

        // Counted wait: tile j's loads are done once <= {younger ops} remain.
        // Younger-than-loads(j) at this point: stores(j-1)=8 + loads(j+1)=8.
        if (j == 0 || j == TPB - 1)
            asm volatile("s_waitcnt vmcnt(8)" ::: "memory");
        else
            asm volatile("s_waitcnt vmcnt(16)" ::: "memory");

        f32x4* cur = &buf[wid][pb][0];

        // Scan: each lane owns neuron row `lane` of this wave-tile;
        // thread-private LDS addresses, in-place writeback.
        float u = 0.0f, o = 0.0f;
#pragma unroll
        for (int jj = 0; jj < QPR; ++jj) {
            const int phys = lane * QPR + (jj ^ (lane & 7));  // == swz(lane*8+jj)
            f32x4 v = cur[phys];
            f32x4 r;

            u = TAU * u * (1.0f - o) + v.x;
            o = (u > VTH) ? 1.0f : 0.0f;
            r.x = o;

            u = TAU * u * (1.0f - o) + v.y;
            o = (u > VTH) ? 1.0f : 0.0f;
            r.y = o;

            u = TAU * u * (1.0f - o) + v.z;
            o = (u > VTH) ? 1.0f : 0.0f;
            r.z = o;

            u = TAU * u * (1.0f - o) + v.w;
            o = (u > VTH) ? 1.0f : 0.0f;
            r.w = o;

            cur[phys] = r;
        }
        // DS is in-order per wave; pin compiler ordering before the
        // cross-lane transposed reads below.
        asm volatile("s_waitcnt lgkmcnt(0)" ::: "memory");

        // Store: coalesced, nontemporal (don't allocate output in L3).
        const size_t tb = block_base + (size_t)j * TILE_F4 + wid * WAVE_F4;
#pragma unroll
        for (int k = 0; k < QPR; ++k) {
            const int s = k * 64 + lane;
            __builtin_nontemporal_store(cur[swz(s)], op + tb + s);
        }
    }
}

extern "C" void kernel_launch(void* const* d_in, const int* in_sizes, int n_in,
                              void* d_out, int out_size, void* d_ws, size_t ws_size,
                              hipStream_t stream) {
    const float* x = (const float*)d_in[0];
    float* out = (float*)d_out;
    int total_f4 = in_sizes[0] / 4;            // 8,388,608
    int n_tiles = total_f4 / TILE_F4;          // 4096
    int grid = n_tiles / TPB;                  // 512 blocks (exact)
    LIFSpike_kernel<<<grid, BLOCK, 0, stream>>>(x, out);
}

// Round 4
// 232.626 us; speedup vs baseline: 1.0035x; 1.0035x over previous
//
#include <hip/hip_runtime.h>

// LIF spike scan: x[N, T=32] fp32, scan over contiguous T axis.
//   u = 0.25*u*(1-o_prev) + x_t ;  o = (u > 0.5) ? 1 : 0
// 0.25*u exact (pow2), (1-o) in {0,1} exact -> bit-exact vs numpy fp32 ref.
//
// R6: zero-LDS register-resident scan, 4 lanes per neuron.
//  - R0/R3/R5 post-mortem: three different LDS-transpose structures all sat
//    at exactly 80.3us (3.3 TB/s combined) while the harness memset hit
//    6.65 TB/s in the same profile. Common factor = the LDS round-trip
//    structure (4 trips/byte, 25-31% occupancy). Remove it.
//  - Layout trick: a neuron row is 128B = 2 cache lines; 4 lanes x 16B =
//    one full 64B line. Lanes 4i..4i+3 own neuron i: lane j loads f4 j and
//    f4 j+4 of the row. Every load/store instruction covers 16 fully-packed
//    64B lines == the copy-ubench coalescing profile. No LDS, no barriers.
//  - Scan runs in 8 segments of 4 timesteps, hopping across the 4 lanes.
//    Carry is only `u`: o = heaviside(u-VTH) is recomputed bit-exactly from
//    the broadcast u (1 __shfl per segment). Lane divergence during the scan
//    (16/64 active) is free -- VALU was 6% busy.
//  - ~32 VGPR, 0 LDS -> full occupancy; NT stores keep the never-re-read
//    output from evicting the input from L3.

constexpr float TAU = 0.25f;
constexpr float VTH = 0.5f;
constexpr int BLOCK = 256;
constexpr int GRID = 2048;          // 8 blocks/CU, grid-stride over chunks

typedef float f32x4 __attribute__((ext_vector_type(4)));

// One chunk = 16 neurons x 32 T = 512 floats = 128 f4 = 2 KB, one wave-iter.

__global__ __launch_bounds__(BLOCK) void LIFSpike_kernel(
    const float* __restrict__ x, float* __restrict__ out, int n_chunks) {
    const int t = threadIdx.x;
    const int lane = t & 63;
    const int j = lane & 3;                      // position within neuron group
    const int g = lane >> 2;                     // neuron group 0..15
    const int wave = blockIdx.x * (BLOCK / 64) + (t >> 6);
    const int nwaves = gridDim.x * (BLOCK / 64);

    const f32x4* __restrict__ xp = reinterpret_cast<const f32x4*>(x);
    f32x4* __restrict__ op = reinterpret_cast<f32x4*>(out);

    for (size_t c = wave; c < (size_t)n_chunks; c += nwaves) {
        // lane's two f4 slots of neuron row (c*16 + g):
        //   r0 -> timesteps 4j..4j+3, r1 -> timesteps 16+4j..16+4j+3
        const size_t a0 = c * 128 + (size_t)g * 8 + j;
        const f32x4 v0 = xp[a0];
        const f32x4 v1 = xp[a0 + 4];
        f32x4 r0, r1;

        float u = 0.0f, o = 0.0f;
#pragma unroll
        for (int s = 0; s < 8; ++s) {
            if (j == (s & 3)) {                  // owner of this 4-step segment
                const f32x4 v = (s < 4) ? v0 : v1;
                float uu = u, oo = o;
                f32x4 r;
                uu = TAU * uu * (1.0f - oo) + v.x;
                oo = (uu > VTH) ? 1.0f : 0.0f;  r.x = oo;
                uu = TAU * uu * (1.0f - oo) + v.y;
                oo = (uu > VTH) ? 1.0f : 0.0f;  r.y = oo;
                uu = TAU * uu * (1.0f - oo) + v.z;
                oo = (uu > VTH) ? 1.0f : 0.0f;  r.z = oo;
                uu = TAU * uu * (1.0f - oo) + v.w;
                oo = (uu > VTH) ? 1.0f : 0.0f;  r.w = oo;
                u = uu;
                if (s < 4) r0 = r; else r1 = r;
            }
            // Broadcast the owner's u to the whole 4-lane group; recompute o.
            u = __shfl(u, (lane & ~3) | (s & 3));
            o = (u > VTH) ? 1.0f : 0.0f;
        }

        __builtin_nontemporal_store(r0, op + a0);
        __builtin_nontemporal_store(r1, op + a0 + 4);
    }
}

extern "C" void kernel_launch(void* const* d_in, const int* in_sizes, int n_in,
                              void* d_out, int out_size, void* d_ws, size_t ws_size,
                              hipStream_t stream) {
    const float* x = (const float*)d_in[0];
    float* out = (float*)d_out;
    int n_chunks = in_sizes[0] / 512;   // 33,554,432 floats -> 65,536 chunks
    LIFSpike_kernel<<<GRID, BLOCK, 0, stream>>>(x, out, n_chunks);
}